// Round 6
// baseline (359.864 us; speedup 1.0000x reference)
//
#include <hip/hip_runtime.h>
#include <stdint.h>

// Problem constants
#define EMB   1024
#define HEADS 16
#define HD    64
#define BB    2
#define TT    2048
#define MTOT  (BB*TT)
#define LDP   72               // padded LDS stride (shorts): 36 dw = 4 banks mod 32

#define ELX (4194304u)         // MTOT*EMB elems
#define ELW (1048576u)         // EMB*EMB elems

#define CSCALE (0.125f * 1.44269504088896f)   // HD^-0.5 * log2(e)

typedef __attribute__((ext_vector_type(8))) short short8;
typedef __attribute__((ext_vector_type(4))) float f32x4;
typedef __attribute__((ext_vector_type(4))) unsigned short us4;

__device__ __forceinline__ float bf2f(ushort u) {
  union { uint32_t u; float f; } x; x.u = ((uint32_t)u) << 16; return x.f;
}
__device__ __forceinline__ ushort f2bf(float f) {
  union { float f; uint32_t u; } x; x.f = f;
  uint32_t u = x.u;
  u += 0x7fffu + ((u >> 16) & 1u);   // RNE
  return (ushort)(u >> 16);
}
__device__ __forceinline__ ushort f2bf_trunc(float f) {
  union { float f; uint32_t u; } x; x.f = f;
  return (ushort)(x.u >> 16);
}
__device__ __forceinline__ uint32_t pack2(uint32_t lo, uint32_t hi) {
  return (lo >> 16) | (hi & 0xFFFF0000u);   // [bf16(lo), bf16(hi)] truncation
}
__device__ __forceinline__ short8 pack8(f32x4 a, f32x4 b) {
  union { f32x4 v; uint32_t u[4]; } A, B;
  A.v = a; B.v = b;
  union { uint32_t d[4]; short8 s; } R;
  R.d[0] = pack2(A.u[0], A.u[1]);
  R.d[1] = pack2(A.u[2], A.u[3]);
  R.d[2] = pack2(B.u[0], B.u[1]);
  R.d[3] = pack2(B.u[2], B.u[3]);
  return R.s;
}
__device__ __forceinline__ short8 cvt8_rne(const float* f) {
  f32x4 a = *(const f32x4*)f;
  f32x4 b = *(const f32x4*)(f + 4);
  short8 r;
  r[0] = (short)f2bf(a[0]); r[1] = (short)f2bf(a[1]);
  r[2] = (short)f2bf(a[2]); r[3] = (short)f2bf(a[3]);
  r[4] = (short)f2bf(b[0]); r[5] = (short)f2bf(b[1]);
  r[6] = (short)f2bf(b[2]); r[7] = (short)f2bf(b[3]);
  return r;
}

// ---------------------------------------------------------------------------
// dtype probe: 1 = bf16 storage, 0 = fp32 storage
// ---------------------------------------------------------------------------
__global__ void detect_dtype(const uint32_t* __restrict__ x, int* __restrict__ flag) {
  if (threadIdx.x == 0) {
    int cnt = 0;
    for (int i = 0; i < 256; ++i) {
      uint32_t lo = x[i] & 0xFFFFu;
      uint32_t e = (lo >> 7) & 0xFFu;
      if (e >= 0x70u && e <= 0x8Fu) ++cnt;
    }
    *flag = (cnt > 128) ? 1 : 0;
  }
}

// convert Wq,Wk,Wv -> contiguous bf16 [3*ELW] (RNE)   grid 1536 x 256
__global__ __launch_bounds__(256) void convert3(const void* __restrict__ w0,
                                                const void* __restrict__ w1,
                                                const void* __restrict__ w2,
                                                ushort* __restrict__ dst,
                                                const int* __restrict__ flag) {
  const size_t i = ((size_t)blockIdx.x * 256 + threadIdx.x) * 8;
  const int wi = (int)(i >> 20);
  const size_t off = i & (ELW - 1);
  const void* src = (wi == 0) ? w0 : (wi == 1) ? w1 : w2;
  if (*flag) *(short8*)(dst + i) = *(const short8*)((const ushort*)src + off);
  else       *(short8*)(dst + i) = cvt8_rne((const float*)src + off);
}

// ---------------------------------------------------------------------------
// QKV GEMM: 128x128 tile, BK=64 (32 MFMAs per barrier pair), padded LDS,
// register prefetch both sides. A = x (fp32 trunc-pack or bf16), B = w3 bf16.
// ---------------------------------------------------------------------------
template<bool ABF>
__device__ __forceinline__ void gemm_qkv(const void* __restrict__ Ap,
                                         const ushort* __restrict__ Wp,
                                         int m0, int n0,
                                         ushort* As, ushort* Ws,
                                         f32x4 acc[4][4]) {
  const int tid  = threadIdx.x;
  const int w    = tid >> 6;
  const int lane = tid & 63;
  const int quad = lane >> 4;
  const int l16  = lane & 15;
  const int wrow = w >> 1, wcol = w & 1;
  const int srow = tid >> 1;            // 0..127
  const int scol = (tid & 1) * 32;      // 0 / 32

  const size_t aoff = (size_t)(m0 + srow) * EMB + scol;
  const size_t boff = (size_t)(n0 + srow) * EMB + scol;

  short8 wa[4];
  short8 ab[4];
  f32x4  af8[8];
  if constexpr (ABF) {
#pragma unroll
    for (int i = 0; i < 4; ++i) ab[i] = *(const short8*)((const ushort*)Ap + aoff + 8 * i);
  } else {
#pragma unroll
    for (int i = 0; i < 8; ++i) af8[i] = *(const f32x4*)((const float*)Ap + aoff + 4 * i);
  }
#pragma unroll
  for (int i = 0; i < 4; ++i) wa[i] = *(const short8*)(Wp + boff + 8 * i);

  for (int k0 = 0; k0 < EMB; k0 += 64) {
    __syncthreads();
    if constexpr (ABF) {
#pragma unroll
      for (int i = 0; i < 4; ++i) *(short8*)&As[srow * LDP + scol + 8 * i] = ab[i];
    } else {
#pragma unroll
      for (int i = 0; i < 4; ++i)
        *(short8*)&As[srow * LDP + scol + 8 * i] = pack8(af8[2 * i], af8[2 * i + 1]);
    }
#pragma unroll
    for (int i = 0; i < 4; ++i) *(short8*)&Ws[srow * LDP + scol + 8 * i] = wa[i];
    if (k0 + 64 < EMB) {
      if constexpr (ABF) {
#pragma unroll
        for (int i = 0; i < 4; ++i)
          ab[i] = *(const short8*)((const ushort*)Ap + aoff + k0 + 64 + 8 * i);
      } else {
#pragma unroll
        for (int i = 0; i < 8; ++i)
          af8[i] = *(const f32x4*)((const float*)Ap + aoff + k0 + 64 + 4 * i);
      }
#pragma unroll
      for (int i = 0; i < 4; ++i) wa[i] = *(const short8*)(Wp + boff + k0 + 64 + 8 * i);
    }
    __syncthreads();

#pragma unroll
    for (int ks = 0; ks < 2; ++ks) {
      short8 af[4], bfr[4];
#pragma unroll
      for (int i = 0; i < 4; ++i)
        af[i]  = *(const short8*)&As[(wrow * 64 + i * 16 + l16) * LDP + ks * 32 + quad * 8];
#pragma unroll
      for (int i = 0; i < 4; ++i)
        bfr[i] = *(const short8*)&Ws[(wcol * 64 + i * 16 + l16) * LDP + ks * 32 + quad * 8];
#pragma unroll
      for (int mi = 0; mi < 4; ++mi)
#pragma unroll
        for (int ni = 0; ni < 4; ++ni)
          acc[mi][ni] = __builtin_amdgcn_mfma_f32_16x16x32_bf16(af[mi], bfr[ni], acc[mi][ni], 0, 0, 0);
    }
  }
}

// QKV epilogue: Q (pre-scaled) / K head-major [B][H][T][HD]; V^T [B][H][HD][T]
__device__ __forceinline__ void qkv_epilogue(f32x4 acc[4][4], int mt, int n0, int mat,
                                             const void* bias, int isbf,
                                             ushort* qo, ushort* ko, ushort* vo) {
  const int tid  = threadIdx.x;
  const int w    = tid >> 6;
  const int lane = tid & 63;
  const int quad = lane >> 4;
  const int l16  = lane & 15;
  const int wrow = w >> 1, wcol = w & 1;
  ushort* dst = (mat == 0) ? qo : ko;
  const float sc = (mat == 0) ? CSCALE : 1.0f;

#pragma unroll
  for (int ni = 0; ni < 4; ++ni) {
    const int n = n0 + wcol * 64 + ni * 16 + l16;
    const float bv_ = isbf ? bf2f(((const ushort*)bias)[n]) : ((const float*)bias)[n];
    const int hh = n >> 6, d = n & 63;
#pragma unroll
    for (int mi = 0; mi < 4; ++mi) {
      const int mbase = mt * 128 + wrow * 64 + mi * 16 + quad * 4;
      const int b = mbase >> 11, t = mbase & (TT - 1);
      if (mat == 2) {
        us4 pk;
#pragma unroll
        for (int r = 0; r < 4; ++r) pk[r] = f2bf(acc[mi][ni][r] + bv_);
        *(us4*)&vo[((size_t)((b * HEADS + hh) * HD + d)) * TT + t] = pk;
      } else {
#pragma unroll
        for (int r = 0; r < 4; ++r)
          dst[((size_t)((b * HEADS + hh) * TT + t + r)) * HD + d] = f2bf((acc[mi][ni][r] + bv_) * sc);
      }
    }
  }
}

__global__ __launch_bounds__(256) void qkv_pipe(const void* __restrict__ x,
                                                const ushort* __restrict__ w3,
                                                const void* __restrict__ bq,
                                                const void* __restrict__ bk,
                                                const void* __restrict__ bv,
                                                ushort* __restrict__ qo,
                                                ushort* __restrict__ ko,
                                                ushort* __restrict__ vo,
                                                const int* __restrict__ flag) {
  __shared__ __align__(16) ushort As[128 * LDP];
  __shared__ __align__(16) ushort Ws[128 * LDP];
  // XCD swizzle: same-mt blocks share an XCD (x-tile L2 locality)
  const int xcd = blockIdx.x & 7;
  const int i   = blockIdx.x >> 3;       // 0..95
  const int mt  = xcd * 4 + i / 24;      // 0..31
  const int nt  = i % 24;
  const int mat = nt >> 3;
  const int n0  = (nt & 7) * 128;
  const ushort* W  = w3 + (size_t)mat * ELW;
  const void* bias = (mat == 0) ? bq : (mat == 1) ? bk : bv;

  f32x4 acc[4][4];
#pragma unroll
  for (int a = 0; a < 4; ++a)
#pragma unroll
    for (int b = 0; b < 4; ++b) acc[a][b] = (f32x4){0.f, 0.f, 0.f, 0.f};

  const int isbf = *flag;
  if (isbf) gemm_qkv<true >(x, W, mt * 128, n0, As, Ws, acc);
  else      gemm_qkv<false>(x, W, mt * 128, n0, As, Ws, acc);
  qkv_epilogue(acc, mt, n0, mat, bias, isbf, qo, ko, vo);
}

// ---------------------------------------------------------------------------
// Barrier-free causal attention. Fixed-max softmax makes K-tiles
// order-independent: wave w processes k-tiles {w, w+4, ...} for ALL 64 q-rows,
// K/V fragments loaded directly from global, P transpose in wave-private LDS.
// No __syncthreads in the loop; one 3-barrier fp32 reduction at the end.
// ---------------------------------------------------------------------------
__global__ __launch_bounds__(256) void attn4(const ushort* __restrict__ qw,
                                             const ushort* __restrict__ kw,
                                             const ushort* __restrict__ vtw,
                                             ushort* __restrict__ out) {
  __shared__ __align__(16) ushort Pbuf[4][64 * LDP];   // per-wave P; reused for reduce
  __shared__ float lsA[64], lsB[64];

  const int bid = blockIdx.x;
  const int j  = bid >> 8;
  const int r8 = bid & 255;
  const int qh = r8 & 31;
  const int bh = j * 8 + (r8 >> 5);
  int qt;
  if      (j == 0) qt = qh;
  else if (j == 1) qt = 31 - qh;
  else if (j == 2) qt = (qh + 16) & 31;
  else             qt = 31 - ((qh + 16) & 31);
  const int h = bh & (HEADS - 1);
  const int b = bh >> 4;

  const int tid  = threadIdx.x;
  const int w    = tid >> 6;
  const int lane = tid & 63;
  const int quad = lane >> 4;
  const int l16  = lane & 15;

  const size_t hoff = ((size_t)(b * HEADS + h)) * TT * HD;
  const ushort* Qg = qw + hoff;
  const ushort* Kg = kw + hoff;
  const ushort* Vg = vtw + hoff;     // [d][T]
  const int q0 = qt * 64;
  ushort* Pw = &Pbuf[w][0];

  // Q A-frags for all 64 q-rows (scale pre-folded by qkv epilogue)
  short8 qa[4][2];
#pragma unroll
  for (int mi = 0; mi < 4; ++mi) {
    const ushort* qrow = Qg + (size_t)(q0 + mi * 16 + l16) * HD + quad * 8;
    qa[mi][0] = *(const short8*)(qrow);
    qa[mi][1] = *(const short8*)(qrow + 32);
  }

  f32x4 o[4][4];
  float ls[4][4];
#pragma unroll
  for (int mi = 0; mi < 4; ++mi) {
#pragma unroll
    for (int ni = 0; ni < 4; ++ni) o[mi][ni] = (f32x4){0.f, 0.f, 0.f, 0.f};
#pragma unroll
    for (int r = 0; r < 4; ++r) ls[mi][r] = 0.f;
  }

  for (int kt = w; kt <= qt; kt += 4) {
    const int k0 = kt * 64;

    // S = Q K^T  (K B-frags direct from global)
    f32x4 s[4][4];
#pragma unroll
    for (int mi = 0; mi < 4; ++mi)
#pragma unroll
      for (int ni = 0; ni < 4; ++ni) s[mi][ni] = (f32x4){0.f, 0.f, 0.f, 0.f};
#pragma unroll
    for (int ks = 0; ks < 2; ++ks) {
#pragma unroll
      for (int ni = 0; ni < 4; ++ni) {
        short8 kb = *(const short8*)(Kg + (size_t)(k0 + ni * 16 + l16) * HD + ks * 32 + quad * 8);
#pragma unroll
        for (int mi = 0; mi < 4; ++mi)
          s[mi][ni] = __builtin_amdgcn_mfma_f32_16x16x32_bf16(qa[mi][ks], kb, s[mi][ni], 0, 0, 0);
      }
    }

    if (kt == qt) {   // diagonal tile mask (k0 == q0)
#pragma unroll
      for (int ni = 0; ni < 4; ++ni) {
        const int kk = ni * 16 + l16;
#pragma unroll
        for (int mi = 0; mi < 4; ++mi)
#pragma unroll
          for (int r = 0; r < 4; ++r)
            if (kk > mi * 16 + quad * 4 + r) s[mi][ni][r] = -__builtin_inff();
      }
    }

    // p = 2^s, accumulate per-lane row partials, write P to wave-private LDS
#pragma unroll
    for (int mi = 0; mi < 4; ++mi)
#pragma unroll
      for (int ni = 0; ni < 4; ++ni)
#pragma unroll
        for (int r = 0; r < 4; ++r) {
          const float p = exp2f(s[mi][ni][r]);
          ls[mi][r] += p;
          Pw[(mi * 16 + quad * 4 + r) * LDP + ni * 16 + l16] = f2bf_trunc(p);
        }

    // O += P V  (P A-frags from LDS, V B-frags direct from global)
#pragma unroll
    for (int ks = 0; ks < 2; ++ks) {
      short8 pa[4];
#pragma unroll
      for (int mi = 0; mi < 4; ++mi)
        pa[mi] = *(const short8*)&Pw[(mi * 16 + l16) * LDP + ks * 32 + quad * 8];
#pragma unroll
      for (int ni = 0; ni < 4; ++ni) {
        short8 vb = *(const short8*)(Vg + (size_t)(ni * 16 + l16) * TT + k0 + ks * 32 + quad * 8);
#pragma unroll
        for (int mi = 0; mi < 4; ++mi)
          o[mi][ni] = __builtin_amdgcn_mfma_f32_16x16x32_bf16(pa[mi], vb, o[mi][ni], 0, 0, 0);
      }
    }
  }

  // ---- cross-wave reduction (fp32, in dead P buffers; stride 68 floats) ----
  float* bufA = (float*)&Pbuf[0][0];
  float* bufB = (float*)&Pbuf[2][0];

  __syncthreads();
  if (w < 2) {
    float* buf = w ? bufB : bufA;
#pragma unroll
    for (int mi = 0; mi < 4; ++mi)
#pragma unroll
      for (int ni = 0; ni < 4; ++ni)
#pragma unroll
        for (int r = 0; r < 4; ++r)
          buf[(mi * 16 + quad * 4 + r) * 68 + ni * 16 + l16] = o[mi][ni][r];
#pragma unroll
    for (int mi = 0; mi < 4; ++mi)
#pragma unroll
      for (int r = 0; r < 4; ++r) {
#pragma unroll
        for (int off = 1; off < 16; off <<= 1) ls[mi][r] += __shfl_xor(ls[mi][r], off);
      }
    if (l16 == 0) {
      float* lsp = w ? lsB : lsA;
#pragma unroll
      for (int mi = 0; mi < 4; ++mi)
#pragma unroll
        for (int r = 0; r < 4; ++r) lsp[mi * 16 + quad * 4 + r] = ls[mi][r];
    }
  }
  __syncthreads();
  if (w >= 2) {
    float* buf = (w == 2) ? bufA : bufB;
#pragma unroll
    for (int mi = 0; mi < 4; ++mi)
#pragma unroll
      for (int ni = 0; ni < 4; ++ni)
#pragma unroll
        for (int r = 0; r < 4; ++r)
          buf[(mi * 16 + quad * 4 + r) * 68 + ni * 16 + l16] += o[mi][ni][r];
#pragma unroll
    for (int mi = 0; mi < 4; ++mi)
#pragma unroll
      for (int r = 0; r < 4; ++r) {
#pragma unroll
        for (int off = 1; off < 16; off <<= 1) ls[mi][r] += __shfl_xor(ls[mi][r], off);
      }
    if (l16 == 0) {
      float* lsp = (w == 2) ? lsA : lsB;
#pragma unroll
      for (int mi = 0; mi < 4; ++mi)
#pragma unroll
        for (int r = 0; r < 4; ++r) lsp[mi * 16 + quad * 4 + r] += ls[mi][r];
    }
  }
  __syncthreads();

  // final: (bufA+bufB)/l -> out[B][T][EMB]
  {
    const int row = tid >> 2;
    const int c0  = (tid & 3) * 16;
    const float inv = 1.0f / (lsA[row] + lsB[row]);
    short8 o0, o1;
#pragma unroll
    for (int k = 0; k < 8; ++k) {
      o0[k] = (short)f2bf((bufA[row * 68 + c0 + k]     + bufB[row * 68 + c0 + k])     * inv);
      o1[k] = (short)f2bf((bufA[row * 68 + c0 + 8 + k] + bufB[row * 68 + c0 + 8 + k]) * inv);
    }
    ushort* op = &out[((size_t)(b * TT + q0 + row)) * EMB + h * HD + c0];
    *(short8*)op = o0;
    *(short8*)(op + 8) = o1;
  }
}

// ---------------------------------------------------------------------------
// Output projection: 64x128 tiles, BK=64, register prefetch, 512 blocks.
// ---------------------------------------------------------------------------
template<bool WBF>
__device__ __forceinline__ void proj_core(const ushort* __restrict__ A,
                                          const void* __restrict__ Wo,
                                          int m0, int n0,
                                          ushort* As, ushort* Ws,
                                          f32x4 acc[4][2]) {
  const int tid  = threadIdx.x;
  const int w    = tid >> 6;
  const int lane = tid & 63;
  const int quad = lane >> 4;
  const int l16  = lane & 15;
  const int arow = tid >> 2;            // 0..63
  const int acol = (tid & 3) * 16;      // 16 elems
  const int wrw  = tid >> 1;            // 0..127
  const int wcl  = (tid & 1) * 32;      // 32 elems

  const size_t aoff = (size_t)(m0 + arow) * EMB + acol;
  const size_t boff = (size_t)(n0 + wrw) * EMB + wcl;

  short8 pa2[2];
  short8 wb[4];
  f32x4  wf8[8];
  pa2[0] = *(const short8*)(A + aoff);
  pa2[1] = *(const short8*)(A + aoff + 8);
  if constexpr (WBF) {
#pragma unroll
    for (int i = 0; i < 4; ++i) wb[i] = *(const short8*)((const ushort*)Wo + boff + 8 * i);
  } else {
#pragma unroll
    for (int i = 0; i < 8; ++i) wf8[i] = *(const f32x4*)((const float*)Wo + boff + 4 * i);
  }

  for (int k0 = 0; k0 < EMB; k0 += 64) {
    __syncthreads();
    *(short8*)&As[arow * LDP + acol]     = pa2[0];
    *(short8*)&As[arow * LDP + acol + 8] = pa2[1];
    if constexpr (WBF) {
#pragma unroll
      for (int i = 0; i < 4; ++i) *(short8*)&Ws[wrw * LDP + wcl + 8 * i] = wb[i];
    } else {
#pragma unroll
      for (int i = 0; i < 4; ++i)
        *(short8*)&Ws[wrw * LDP + wcl + 8 * i] = pack8(wf8[2 * i], wf8[2 * i + 1]);
    }
    if (k0 + 64 < EMB) {
      pa2[0] = *(const short8*)(A + aoff + k0 + 64);
      pa2[1] = *(const short8*)(A + aoff + k0 + 64 + 8);
      if constexpr (WBF) {
#pragma unroll
        for (int i = 0; i < 4; ++i)
          wb[i] = *(const short8*)((const ushort*)Wo + boff + k0 + 64 + 8 * i);
      } else {
#pragma unroll
        for (int i = 0; i < 8; ++i)
          wf8[i] = *(const f32x4*)((const float*)Wo + boff + k0 + 64 + 4 * i);
      }
    }
    __syncthreads();

#pragma unroll
    for (int ks = 0; ks < 2; ++ks) {
      short8 af[4], bfr[2];
#pragma unroll
      for (int i = 0; i < 4; ++i)
        af[i]  = *(const short8*)&As[(i * 16 + l16) * LDP + ks * 32 + quad * 8];
#pragma unroll
      for (int i = 0; i < 2; ++i)
        bfr[i] = *(const short8*)&Ws[(w * 32 + i * 16 + l16) * LDP + ks * 32 + quad * 8];
#pragma unroll
      for (int mi = 0; mi < 4; ++mi)
#pragma unroll
        for (int ni = 0; ni < 2; ++ni)
          acc[mi][ni] = __builtin_amdgcn_mfma_f32_16x16x32_bf16(af[mi], bfr[ni], acc[mi][ni], 0, 0, 0);
    }
  }
}

__global__ __launch_bounds__(256) void proj_pipe(const ushort* __restrict__ A,
                                                 const void* __restrict__ Wo,
                                                 const void* __restrict__ bo,
                                                 void* __restrict__ out,
                                                 const int* __restrict__ flag) {
  __shared__ __align__(16) ushort As[64 * LDP];
  __shared__ __align__(16) ushort Ws[128 * LDP];
  const int xcd = blockIdx.x & 7;
  const int i   = blockIdx.x >> 3;       // 0..63
  const int mt  = xcd * 8 + (i >> 3);    // 0..63 (64-row tiles)
  const int nt  = i & 7;
  const int n0  = nt * 128;
  const int m0  = mt * 64;

  f32x4 acc[4][2];
#pragma unroll
  for (int a = 0; a < 4; ++a)
#pragma unroll
    for (int b = 0; b < 2; ++b) acc[a][b] = (f32x4){0.f, 0.f, 0.f, 0.f};

  const int isbf = *flag;
  if (isbf) proj_core<true >(A, Wo, m0, n0, As, Ws, acc);
  else      proj_core<false>(A, Wo, m0, n0, As, Ws, acc);

  const int tid  = threadIdx.x;
  const int w    = tid >> 6;
  const int lane = tid & 63;
  const int quad = lane >> 4;
  const int l16  = lane & 15;

#pragma unroll
  for (int ni = 0; ni < 2; ++ni) {
    const int n = n0 + w * 32 + ni * 16 + l16;
    const float bv_ = isbf ? bf2f(((const ushort*)bo)[n]) : ((const float*)bo)[n];
#pragma unroll
    for (int mi = 0; mi < 4; ++mi) {
#pragma unroll
      for (int r = 0; r < 4; ++r) {
        const int m = m0 + mi * 16 + quad * 4 + r;
        const float v = acc[mi][ni][r] + bv_;
        if (isbf) ((ushort*)out)[(size_t)m * EMB + n] = f2bf(v);
        else      ((float*) out)[(size_t)m * EMB + n] = v;
      }
    }
  }
}

// ---------------------------------------------------------------------------
extern "C" void kernel_launch(void* const* d_in, const int* in_sizes, int n_in,
                              void* d_out, int out_size, void* d_ws, size_t ws_size,
                              hipStream_t stream) {
  const void* x  = d_in[0];
  const void* Wq = d_in[1];
  const void* bq = d_in[2];
  const void* Wk = d_in[3];
  const void* bk = d_in[4];
  const void* Wv = d_in[5];
  const void* bv = d_in[6];
  const void* Wo = d_in[7];
  const void* bo = d_in[8];

  int* flag = (int*)d_ws;
  ushort* base = (ushort*)((char*)d_ws + 256);

  // ws layout (33.56 MB budget):
  //   q:[0,ELX) k:[ELX,2ELX) vt:[2ELX,3ELX)
  //   w3 (3*ELW, dead after qkv) and o (ELX) share [3ELX,4ELX)
  ushort* q_ws  = base;
  ushort* k_ws  = q_ws + ELX;
  ushort* vt_ws = k_ws + ELX;
  ushort* w3    = vt_ws + ELX;
  ushort* o_ws  = vt_ws + ELX;

  detect_dtype<<<dim3(1), dim3(64), 0, stream>>>((const uint32_t*)x, flag);
  convert3<<<dim3(1536), dim3(256), 0, stream>>>(Wq, Wk, Wv, w3, flag);
  qkv_pipe<<<dim3(768), dim3(256), 0, stream>>>(x, w3, bq, bk, bv,
                                                q_ws, k_ws, vt_ws, flag);
  attn4<<<dim3(1024), dim3(256), 0, stream>>>(q_ws, k_ws, vt_ws, o_ws);
  proj_pipe<<<dim3(512), dim3(256), 0, stream>>>(o_ws, Wo, bo, d_out, flag);
}

// Round 7
// 228.153 us; speedup vs baseline: 1.5773x; 1.5773x over previous
//
#include <hip/hip_runtime.h>
#include <stdint.h>

// Problem constants
#define EMB   1024
#define HEADS 16
#define HD    64
#define BB    2
#define TT    2048
#define MTOT  (BB*TT)
#define LDA   72               // padded LDS stride for attention tiles
#define LDP   72               // padded LDS stride for qkv tiles (16B-aligned rows)

#define ELX (4194304u)         // MTOT*EMB elems
#define ELW (1048576u)         // EMB*EMB elems

#define CSCALE (0.125f * 1.44269504088896f)   // HD^-0.5 * log2(e)

typedef __attribute__((ext_vector_type(8))) short short8;
typedef __attribute__((ext_vector_type(4))) float f32x4;
typedef __attribute__((ext_vector_type(4))) unsigned short us4;

__device__ __forceinline__ float bf2f(ushort u) {
  union { uint32_t u; float f; } x; x.u = ((uint32_t)u) << 16; return x.f;
}
__device__ __forceinline__ ushort f2bf(float f) {
  union { float f; uint32_t u; } x; x.f = f;
  uint32_t u = x.u;
  u += 0x7fffu + ((u >> 16) & 1u);   // RNE
  return (ushort)(u >> 16);
}
__device__ __forceinline__ ushort f2bf_trunc(float f) {
  union { float f; uint32_t u; } x; x.f = f;
  return (ushort)(x.u >> 16);
}
__device__ __forceinline__ uint32_t pack2(uint32_t lo, uint32_t hi) {
  return (lo >> 16) | (hi & 0xFFFF0000u);   // [bf16(lo), bf16(hi)] truncation
}
__device__ __forceinline__ short8 pack8(f32x4 a, f32x4 b) {
  union { f32x4 v; uint32_t u[4]; } A, B;
  A.v = a; B.v = b;
  union { uint32_t d[4]; short8 s; } R;
  R.d[0] = pack2(A.u[0], A.u[1]);
  R.d[1] = pack2(A.u[2], A.u[3]);
  R.d[2] = pack2(B.u[0], B.u[1]);
  R.d[3] = pack2(B.u[2], B.u[3]);
  return R.s;
}
__device__ __forceinline__ short8 cvt8_rne(const float* f) {
  f32x4 a = *(const f32x4*)f;
  f32x4 b = *(const f32x4*)(f + 4);
  short8 r;
  r[0] = (short)f2bf(a[0]); r[1] = (short)f2bf(a[1]);
  r[2] = (short)f2bf(a[2]); r[3] = (short)f2bf(a[3]);
  r[4] = (short)f2bf(b[0]); r[5] = (short)f2bf(b[1]);
  r[6] = (short)f2bf(b[2]); r[7] = (short)f2bf(b[3]);
  return r;
}

// ---------------------------------------------------------------------------
// dtype probe: 1 = bf16 storage, 0 = fp32 storage
// ---------------------------------------------------------------------------
__global__ void detect_dtype(const uint32_t* __restrict__ x, int* __restrict__ flag) {
  if (threadIdx.x == 0) {
    int cnt = 0;
    for (int i = 0; i < 256; ++i) {
      uint32_t lo = x[i] & 0xFFFFu;
      uint32_t e = (lo >> 7) & 0xFFu;
      if (e >= 0x70u && e <= 0x8Fu) ++cnt;
    }
    *flag = (cnt > 128) ? 1 : 0;
  }
}

// convert Wq,Wk,Wv -> contiguous bf16 [3*ELW] (RNE)   grid 1536 x 256
__global__ __launch_bounds__(256) void convert3(const void* __restrict__ w0,
                                                const void* __restrict__ w1,
                                                const void* __restrict__ w2,
                                                ushort* __restrict__ dst,
                                                const int* __restrict__ flag) {
  const size_t i = ((size_t)blockIdx.x * 256 + threadIdx.x) * 8;
  const int wi = (int)(i >> 20);
  const size_t off = i & (ELW - 1);
  const void* src = (wi == 0) ? w0 : (wi == 1) ? w1 : w2;
  if (*flag) *(short8*)(dst + i) = *(const short8*)((const ushort*)src + off);
  else       *(short8*)(dst + i) = cvt8_rne((const float*)src + off);
}

// ---------------------------------------------------------------------------
// QKV GEMM: 64x128 tile (M=64), BK=64, padded LDS, register prefetch.
// 1536 blocks = 6/CU for cross-block barrier overlap. Wave w computes
// 64 x [w*32, w*32+32) as acc[4][2]; 16 MFMAs/wave per barrier pair.
// ---------------------------------------------------------------------------
template<bool ABF>
__device__ __forceinline__ void gemm_qkv64(const void* __restrict__ Ap,
                                           const ushort* __restrict__ Wp,
                                           int m0, int n0,
                                           ushort* As, ushort* Ws,
                                           f32x4 acc[4][2]) {
  const int tid  = threadIdx.x;
  const int w    = tid >> 6;
  const int lane = tid & 63;
  const int quad = lane >> 4;
  const int l16  = lane & 15;
  const int arow = tid >> 2;            // 0..63
  const int acol = (tid & 3) * 16;      // 16 elems
  const int brow = tid >> 1;            // 0..127
  const int bcol = (tid & 1) * 32;      // 32 elems

  const size_t aoff = (size_t)(m0 + arow) * EMB + acol;
  const size_t boff = (size_t)(n0 + brow) * EMB + bcol;

  short8 ab[2];
  f32x4  af[4];
  short8 wb[4];
  if constexpr (ABF) {
    ab[0] = *(const short8*)((const ushort*)Ap + aoff);
    ab[1] = *(const short8*)((const ushort*)Ap + aoff + 8);
  } else {
#pragma unroll
    for (int i = 0; i < 4; ++i) af[i] = *(const f32x4*)((const float*)Ap + aoff + 4 * i);
  }
#pragma unroll
  for (int i = 0; i < 4; ++i) wb[i] = *(const short8*)(Wp + boff + 8 * i);

  for (int k0 = 0; k0 < EMB; k0 += 64) {
    __syncthreads();
    if constexpr (ABF) {
      *(short8*)&As[arow * LDP + acol]     = ab[0];
      *(short8*)&As[arow * LDP + acol + 8] = ab[1];
    } else {
      *(short8*)&As[arow * LDP + acol]     = pack8(af[0], af[1]);
      *(short8*)&As[arow * LDP + acol + 8] = pack8(af[2], af[3]);
    }
#pragma unroll
    for (int i = 0; i < 4; ++i) *(short8*)&Ws[brow * LDP + bcol + 8 * i] = wb[i];
    if (k0 + 64 < EMB) {
      if constexpr (ABF) {
        ab[0] = *(const short8*)((const ushort*)Ap + aoff + k0 + 64);
        ab[1] = *(const short8*)((const ushort*)Ap + aoff + k0 + 64 + 8);
      } else {
#pragma unroll
        for (int i = 0; i < 4; ++i)
          af[i] = *(const f32x4*)((const float*)Ap + aoff + k0 + 64 + 4 * i);
      }
#pragma unroll
      for (int i = 0; i < 4; ++i) wb[i] = *(const short8*)(Wp + boff + k0 + 64 + 8 * i);
    }
    __syncthreads();

#pragma unroll
    for (int ks = 0; ks < 2; ++ks) {
      short8 a_[4], b_[2];
#pragma unroll
      for (int i = 0; i < 4; ++i)
        a_[i] = *(const short8*)&As[(i * 16 + l16) * LDP + ks * 32 + quad * 8];
#pragma unroll
      for (int i = 0; i < 2; ++i)
        b_[i] = *(const short8*)&Ws[(w * 32 + i * 16 + l16) * LDP + ks * 32 + quad * 8];
#pragma unroll
      for (int mi = 0; mi < 4; ++mi)
#pragma unroll
        for (int ni = 0; ni < 2; ++ni)
          acc[mi][ni] = __builtin_amdgcn_mfma_f32_16x16x32_bf16(a_[mi], b_[ni], acc[mi][ni], 0, 0, 0);
    }
  }
}

// QKV epilogue (64-row tile): Q (pre-scaled) / K head-major; V^T [B][H][HD][T]
__device__ __forceinline__ void qkv_epi64(f32x4 acc[4][2], int mt, int n0, int mat,
                                          const void* bias, int isbf,
                                          ushort* qo, ushort* ko, ushort* vo) {
  const int tid  = threadIdx.x;
  const int w    = tid >> 6;
  const int lane = tid & 63;
  const int quad = lane >> 4;
  const int l16  = lane & 15;
  ushort* dst = (mat == 0) ? qo : ko;
  const float sc = (mat == 0) ? CSCALE : 1.0f;

#pragma unroll
  for (int ni = 0; ni < 2; ++ni) {
    const int n = n0 + w * 32 + ni * 16 + l16;
    const float bv_ = isbf ? bf2f(((const ushort*)bias)[n]) : ((const float*)bias)[n];
    const int hh = n >> 6, d = n & 63;
#pragma unroll
    for (int mi = 0; mi < 4; ++mi) {
      const int mbase = mt * 64 + mi * 16 + quad * 4;
      const int b = mbase >> 11, t = mbase & (TT - 1);
      if (mat == 2) {
        us4 pk;
#pragma unroll
        for (int r = 0; r < 4; ++r) pk[r] = f2bf(acc[mi][ni][r] + bv_);
        *(us4*)&vo[((size_t)((b * HEADS + hh) * HD + d)) * TT + t] = pk;
      } else {
#pragma unroll
        for (int r = 0; r < 4; ++r)
          dst[((size_t)((b * HEADS + hh) * TT + t + r)) * HD + d] = f2bf((acc[mi][ni][r] + bv_) * sc);
      }
    }
  }
}

__global__ __launch_bounds__(256) void qkv_pipe(const void* __restrict__ x,
                                                const ushort* __restrict__ w3,
                                                const void* __restrict__ bq,
                                                const void* __restrict__ bk,
                                                const void* __restrict__ bv,
                                                ushort* __restrict__ qo,
                                                ushort* __restrict__ ko,
                                                ushort* __restrict__ vo,
                                                const int* __restrict__ flag) {
  __shared__ __align__(16) ushort As[64 * LDP];
  __shared__ __align__(16) ushort Ws[128 * LDP];
  // XCD swizzle: each XCD covers 3 n-tiles -> its 0.75 MB W-slice is L2-resident
  const int xcd = blockIdx.x & 7;
  const int i   = blockIdx.x >> 3;       // 0..191
  const int nt  = xcd * 3 + (i % 3);     // 0..23
  const int mt  = i / 3;                 // 0..63
  const int mat = nt >> 3;
  const int n0  = (nt & 7) * 128;
  const ushort* W  = w3 + (size_t)mat * ELW;
  const void* bias = (mat == 0) ? bq : (mat == 1) ? bk : bv;

  f32x4 acc[4][2];
#pragma unroll
  for (int a = 0; a < 4; ++a)
#pragma unroll
    for (int b = 0; b < 2; ++b) acc[a][b] = (f32x4){0.f, 0.f, 0.f, 0.f};

  const int isbf = *flag;
  if (isbf) gemm_qkv64<true >(x, W, mt * 64, n0, As, Ws, acc);
  else      gemm_qkv64<false>(x, W, mt * 64, n0, As, Ws, acc);
  qkv_epi64(acc, mt, n0, mat, bias, isbf, qo, ko, vo);
}

// ---------------------------------------------------------------------------
// Causal flash attention with register-prefetched K/V staging (R5 version).
// Fixed-max softmax. Balanced qt swizzle.
// ---------------------------------------------------------------------------
__global__ __launch_bounds__(256) void attn3(const ushort* __restrict__ qw,
                                             const ushort* __restrict__ kw,
                                             const ushort* __restrict__ vtw,
                                             ushort* __restrict__ out) {
  __shared__ __align__(16) ushort Ks[64 * LDA];
  __shared__ __align__(16) ushort Vts[64 * LDA];
  __shared__ __align__(16) ushort Ps[4][16 * LDA];

  const int bid = blockIdx.x;
  const int j  = bid >> 8;
  const int r8 = bid & 255;
  const int qh = r8 & 31;
  const int bh = j * 8 + (r8 >> 5);
  int qt;
  if      (j == 0) qt = qh;
  else if (j == 1) qt = 31 - qh;
  else if (j == 2) qt = (qh + 16) & 31;
  else             qt = 31 - ((qh + 16) & 31);
  const int h = bh & (HEADS - 1);
  const int b = bh >> 4;

  const int tid  = threadIdx.x;
  const int w    = tid >> 6;
  const int lane = tid & 63;
  const int quad = lane >> 4;
  const int l16  = lane & 15;

  const size_t hoff = ((size_t)(b * HEADS + h)) * TT * HD;
  const ushort* Qg = qw + hoff;
  const ushort* Kg = kw + hoff;
  const ushort* Vg = vtw + hoff;     // [d][T]
  const int q0 = qt * 64;

  short8 qf[2];
  {
    const ushort* qrow = Qg + (size_t)(q0 + w * 16 + l16) * HD;
    qf[0] = *(const short8*)(qrow + quad * 8);
    qf[1] = *(const short8*)(qrow + 32 + quad * 8);
  }

  const int row = tid >> 2;
  const int c0  = (tid & 3) * 16;
  const ushort* Kbase = Kg + (size_t)row * HD + c0;
  const ushort* Vbase = Vg + (size_t)row * TT + c0;

  short8 pk0 = *(const short8*)(Kbase);
  short8 pk1 = *(const short8*)(Kbase + 8);
  short8 pv0 = *(const short8*)(Vbase);
  short8 pv1 = *(const short8*)(Vbase + 8);

  float ls[4] = {0.f, 0.f, 0.f, 0.f};
  f32x4 O[4];
#pragma unroll
  for (int ni = 0; ni < 4; ++ni) O[ni] = (f32x4){0.f, 0.f, 0.f, 0.f};

  for (int kt = 0; kt <= qt; ++kt) {
    const int k0 = kt * 64;
    __syncthreads();
    *(short8*)&Ks[row * LDA + c0]      = pk0;
    *(short8*)&Ks[row * LDA + c0 + 8]  = pk1;
    *(short8*)&Vts[row * LDA + c0]     = pv0;
    *(short8*)&Vts[row * LDA + c0 + 8] = pv1;
    if (kt < qt) {
      const size_t ko_ = (size_t)(k0 + 64) * HD;
      pk0 = *(const short8*)(Kbase + ko_);
      pk1 = *(const short8*)(Kbase + ko_ + 8);
      pv0 = *(const short8*)(Vbase + k0 + 64);
      pv1 = *(const short8*)(Vbase + k0 + 64 + 8);
    }
    __syncthreads();

    f32x4 s[4];
#pragma unroll
    for (int ni = 0; ni < 4; ++ni) s[ni] = (f32x4){0.f, 0.f, 0.f, 0.f};
#pragma unroll
    for (int ks = 0; ks < 2; ++ks) {
#pragma unroll
      for (int ni = 0; ni < 4; ++ni) {
        short8 kb = *(const short8*)&Ks[(ni * 16 + l16) * LDA + ks * 32 + quad * 8];
        s[ni] = __builtin_amdgcn_mfma_f32_16x16x32_bf16(qf[ks], kb, s[ni], 0, 0, 0);
      }
    }

    if (kt == qt) {
#pragma unroll
      for (int ni = 0; ni < 4; ++ni) {
        const int kk = k0 + ni * 16 + l16;
#pragma unroll
        for (int r = 0; r < 4; ++r) {
          const int qq = q0 + w * 16 + quad * 4 + r;
          if (kk > qq) s[ni][r] = -__builtin_inff();
        }
      }
    }

#pragma unroll
    for (int ni = 0; ni < 4; ++ni)
#pragma unroll
      for (int r = 0; r < 4; ++r) {
        const float p = exp2f(s[ni][r]);
        s[ni][r] = p;
        ls[r] += p;
      }

#pragma unroll
    for (int ni = 0; ni < 4; ++ni)
#pragma unroll
      for (int r = 0; r < 4; ++r)
        Ps[w][(quad * 4 + r) * LDA + ni * 16 + l16] = f2bf_trunc(s[ni][r]);

#pragma unroll
    for (int ks = 0; ks < 2; ++ks) {
      short8 a = *(const short8*)&Ps[w][l16 * LDA + ks * 32 + quad * 8];
#pragma unroll
      for (int ni = 0; ni < 4; ++ni) {
        short8 vb = *(const short8*)&Vts[(ni * 16 + l16) * LDA + ks * 32 + quad * 8];
        O[ni] = __builtin_amdgcn_mfma_f32_16x16x32_bf16(a, vb, O[ni], 0, 0, 0);
      }
    }
  }

#pragma unroll
  for (int r = 0; r < 4; ++r) {
#pragma unroll
    for (int off = 1; off < 16; off <<= 1) ls[r] += __shfl_xor(ls[r], off);
    const float inv = 1.0f / ls[r];
    const int t = q0 + w * 16 + quad * 4 + r;
#pragma unroll
    for (int ni = 0; ni < 4; ++ni) {
      out[((size_t)(b * TT + t)) * EMB + h * HD + ni * 16 + l16] = f2bf(O[ni][r] * inv);
    }
  }
}

// ---------------------------------------------------------------------------
// Output projection: 64x128 tiles, BK=32, register prefetch, 512 blocks (R5).
// ---------------------------------------------------------------------------
template<bool BF> struct PF {
  short8 b0, b1;
  f32x4 f0, f1, f2, f3;
  __device__ __forceinline__ void load(const void* base, size_t i0, size_t i1) {
    if constexpr (BF) {
      b0 = *(const short8*)((const ushort*)base + i0);
      b1 = *(const short8*)((const ushort*)base + i1);
    } else {
      const float* p0 = (const float*)base + i0;
      const float* p1 = (const float*)base + i1;
      f0 = *(const f32x4*)p0; f1 = *(const f32x4*)(p0 + 4);
      f2 = *(const f32x4*)p1; f3 = *(const f32x4*)(p1 + 4);
    }
  }
  __device__ __forceinline__ void store(ushort* l0, ushort* l1) {
    if constexpr (BF) { *(short8*)l0 = b0; *(short8*)l1 = b1; }
    else { *(short8*)l0 = pack8(f0, f1); *(short8*)l1 = pack8(f2, f3); }
  }
};

template<bool WBF>
__device__ __forceinline__ void proj_core(const ushort* __restrict__ A,
                                          const void* __restrict__ Wo,
                                          int m0, int n0,
                                          ushort* As, ushort* Ws,
                                          f32x4 acc[4][2]) {
  const int tid  = threadIdx.x;
  const int w    = tid >> 6;
  const int lane = tid & 63;
  const int quad = lane >> 4;
  const int l16  = lane & 15;
  const int srow = tid >> 2;
  const int scol = (tid & 3) * 8;

  const size_t ai = (size_t)(m0 + srow) * EMB + scol;
  const size_t b0 = (size_t)(n0 + srow) * EMB + scol;
  const size_t b1 = (size_t)(n0 + srow + 64) * EMB + scol;

  short8 pa;
  PF<WBF> pb;
  pa = *(const short8*)(A + ai);
  pb.load(Wo, b0, b1);

  for (int k0 = 0; k0 < EMB; k0 += 32) {
    __syncthreads();
    *(short8*)&As[srow * 32 + scol] = pa;
    pb.store(&Ws[srow * 32 + scol], &Ws[(srow + 64) * 32 + scol]);
    if (k0 + 32 < EMB) {
      pa = *(const short8*)(A + ai + k0 + 32);
      pb.load(Wo, b0 + k0 + 32, b1 + k0 + 32);
    }
    __syncthreads();

    short8 af[4], bfr[2];
#pragma unroll
    for (int i = 0; i < 4; ++i)
      af[i]  = *(const short8*)&As[(i * 16 + l16) * 32 + quad * 8];
#pragma unroll
    for (int i = 0; i < 2; ++i)
      bfr[i] = *(const short8*)&Ws[(w * 32 + i * 16 + l16) * 32 + quad * 8];
#pragma unroll
    for (int mi = 0; mi < 4; ++mi)
#pragma unroll
      for (int ni = 0; ni < 2; ++ni)
        acc[mi][ni] = __builtin_amdgcn_mfma_f32_16x16x32_bf16(af[mi], bfr[ni], acc[mi][ni], 0, 0, 0);
  }
}

__global__ __launch_bounds__(256) void proj_pipe(const ushort* __restrict__ A,
                                                 const void* __restrict__ Wo,
                                                 const void* __restrict__ bo,
                                                 void* __restrict__ out,
                                                 const int* __restrict__ flag) {
  __shared__ __align__(16) ushort As[64 * 32];
  __shared__ __align__(16) ushort Ws[128 * 32];
  const int nt = blockIdx.x & 7;
  const int mt = blockIdx.x >> 3;
  const int n0 = nt * 128;
  const int m0 = mt * 64;

  f32x4 acc[4][2];
#pragma unroll
  for (int i = 0; i < 4; ++i)
#pragma unroll
    for (int jj = 0; jj < 2; ++jj) acc[i][jj] = (f32x4){0.f, 0.f, 0.f, 0.f};

  const int isbf = *flag;
  if (isbf) proj_core<true >(A, Wo, m0, n0, As, Ws, acc);
  else      proj_core<false>(A, Wo, m0, n0, As, Ws, acc);

  const int tid  = threadIdx.x;
  const int w    = tid >> 6;
  const int lane = tid & 63;
  const int quad = lane >> 4;
  const int l16  = lane & 15;

#pragma unroll
  for (int ni = 0; ni < 2; ++ni) {
    const int n = n0 + w * 32 + ni * 16 + l16;
    const float bv_ = isbf ? bf2f(((const ushort*)bo)[n]) : ((const float*)bo)[n];
#pragma unroll
    for (int mi = 0; mi < 4; ++mi) {
#pragma unroll
      for (int r = 0; r < 4; ++r) {
        const int m = m0 + mi * 16 + quad * 4 + r;
        const float v = acc[mi][ni][r] + bv_;
        if (isbf) ((ushort*)out)[(size_t)m * EMB + n] = f2bf(v);
        else      ((float*) out)[(size_t)m * EMB + n] = v;
      }
    }
  }
}

// ---------------------------------------------------------------------------
extern "C" void kernel_launch(void* const* d_in, const int* in_sizes, int n_in,
                              void* d_out, int out_size, void* d_ws, size_t ws_size,
                              hipStream_t stream) {
  const void* x  = d_in[0];
  const void* Wq = d_in[1];
  const void* bq = d_in[2];
  const void* Wk = d_in[3];
  const void* bk = d_in[4];
  const void* Wv = d_in[5];
  const void* bv = d_in[6];
  const void* Wo = d_in[7];
  const void* bo = d_in[8];

  int* flag = (int*)d_ws;
  ushort* base = (ushort*)((char*)d_ws + 256);

  // ws layout (33.56 MB budget):
  //   q:[0,ELX) k:[ELX,2ELX) vt:[2ELX,3ELX)
  //   w3 (3*ELW, dead after qkv) and o (ELX) share [3ELX,4ELX)
  ushort* q_ws  = base;
  ushort* k_ws  = q_ws + ELX;
  ushort* vt_ws = k_ws + ELX;
  ushort* w3    = vt_ws + ELX;
  ushort* o_ws  = vt_ws + ELX;

  detect_dtype<<<dim3(1), dim3(64), 0, stream>>>((const uint32_t*)x, flag);
  convert3<<<dim3(1536), dim3(256), 0, stream>>>(Wq, Wk, Wv, w3, flag);
  qkv_pipe<<<dim3(1536), dim3(256), 0, stream>>>(x, w3, bq, bk, bv,
                                                 q_ws, k_ws, vt_ws, flag);
  attn3<<<dim3(1024), dim3(256), 0, stream>>>(q_ws, k_ws, vt_ws, o_ws);
  proj_pipe<<<dim3(512), dim3(256), 0, stream>>>(o_ws, Wo, bo, d_out, flag);
}

// Round 8
// 222.191 us; speedup vs baseline: 1.6196x; 1.0268x over previous
//
#include <hip/hip_runtime.h>
#include <stdint.h>

// Problem constants
#define EMB   1024
#define HEADS 16
#define HD    64
#define BB    2
#define TT    2048
#define MTOT  (BB*TT)
#define LDA   72               // padded LDS stride for attention tiles
#define LDP   72               // padded LDS stride for qkv tiles (16B-aligned rows)

#define ELX (4194304u)         // MTOT*EMB elems
#define ELW (1048576u)         // EMB*EMB elems

#define CSCALE (0.125f * 1.44269504088896f)   // HD^-0.5 * log2(e)

typedef __attribute__((ext_vector_type(8))) short short8;
typedef __attribute__((ext_vector_type(4))) float f32x4;
typedef __attribute__((ext_vector_type(4))) unsigned short us4;

__device__ __forceinline__ float bf2f(ushort u) {
  union { uint32_t u; float f; } x; x.u = ((uint32_t)u) << 16; return x.f;
}
__device__ __forceinline__ ushort f2bf(float f) {
  union { float f; uint32_t u; } x; x.f = f;
  uint32_t u = x.u;
  u += 0x7fffu + ((u >> 16) & 1u);   // RNE
  return (ushort)(u >> 16);
}
__device__ __forceinline__ ushort f2bf_trunc(float f) {
  union { float f; uint32_t u; } x; x.f = f;
  return (ushort)(x.u >> 16);
}
__device__ __forceinline__ uint32_t pack2(uint32_t lo, uint32_t hi) {
  return (lo >> 16) | (hi & 0xFFFF0000u);   // [bf16(lo), bf16(hi)] truncation
}
__device__ __forceinline__ short8 pack8(f32x4 a, f32x4 b) {
  union { f32x4 v; uint32_t u[4]; } A, B;
  A.v = a; B.v = b;
  union { uint32_t d[4]; short8 s; } R;
  R.d[0] = pack2(A.u[0], A.u[1]);
  R.d[1] = pack2(A.u[2], A.u[3]);
  R.d[2] = pack2(B.u[0], B.u[1]);
  R.d[3] = pack2(B.u[2], B.u[3]);
  return R.s;
}
__device__ __forceinline__ short8 cvt8_rne(const float* f) {
  f32x4 a = *(const f32x4*)f;
  f32x4 b = *(const f32x4*)(f + 4);
  short8 r;
  r[0] = (short)f2bf(a[0]); r[1] = (short)f2bf(a[1]);
  r[2] = (short)f2bf(a[2]); r[3] = (short)f2bf(a[3]);
  r[4] = (short)f2bf(b[0]); r[5] = (short)f2bf(b[1]);
  r[6] = (short)f2bf(b[2]); r[7] = (short)f2bf(b[3]);
  return r;
}

// ---------------------------------------------------------------------------
// dtype probe: 1 = bf16 storage, 0 = fp32 storage.
// PARALLEL version (R7's single-thread serial loop cost ~60 us!): 64 lanes x
// 4 dwords, same predicate (exponent of LOW 16 bits in [0x70,0x8F]),
// wave shuffle-reduce, lane 0 writes.
// ---------------------------------------------------------------------------
__global__ void detect_dtype(const uint32_t* __restrict__ x, int* __restrict__ flag) {
  const int lane = threadIdx.x & 63;
  int cnt = 0;
#pragma unroll
  for (int i = 0; i < 4; ++i) {
    const uint32_t v = x[lane * 4 + i];
    const uint32_t e = ((v & 0xFFFFu) >> 7) & 0xFFu;
    cnt += (e >= 0x70u && e <= 0x8Fu) ? 1 : 0;
  }
#pragma unroll
  for (int off = 1; off < 64; off <<= 1) cnt += __shfl_xor(cnt, off);
  if (lane == 0) *flag = (cnt > 128) ? 1 : 0;
}

// convert Wq,Wk,Wv -> contiguous bf16 [3*ELW] (RNE)   grid 1536 x 256
__global__ __launch_bounds__(256) void convert3(const void* __restrict__ w0,
                                                const void* __restrict__ w1,
                                                const void* __restrict__ w2,
                                                ushort* __restrict__ dst,
                                                const int* __restrict__ flag) {
  const size_t i = ((size_t)blockIdx.x * 256 + threadIdx.x) * 8;
  const int wi = (int)(i >> 20);
  const size_t off = i & (ELW - 1);
  const void* src = (wi == 0) ? w0 : (wi == 1) ? w1 : w2;
  if (*flag) *(short8*)(dst + i) = *(const short8*)((const ushort*)src + off);
  else       *(short8*)(dst + i) = cvt8_rne((const float*)src + off);
}

// ---------------------------------------------------------------------------
// QKV GEMM: 64x128 tile (M=64), BK=64, padded LDS, register prefetch.
// 1536 blocks = 6/CU for cross-block barrier overlap. Wave w computes
// 64 x [w*32, w*32+32) as acc[4][2]; 16 MFMAs/wave per barrier pair.
// ---------------------------------------------------------------------------
template<bool ABF>
__device__ __forceinline__ void gemm_qkv64(const void* __restrict__ Ap,
                                           const ushort* __restrict__ Wp,
                                           int m0, int n0,
                                           ushort* As, ushort* Ws,
                                           f32x4 acc[4][2]) {
  const int tid  = threadIdx.x;
  const int w    = tid >> 6;
  const int lane = tid & 63;
  const int quad = lane >> 4;
  const int l16  = lane & 15;
  const int arow = tid >> 2;            // 0..63
  const int acol = (tid & 3) * 16;      // 16 elems
  const int brow = tid >> 1;            // 0..127
  const int bcol = (tid & 1) * 32;      // 32 elems

  const size_t aoff = (size_t)(m0 + arow) * EMB + acol;
  const size_t boff = (size_t)(n0 + brow) * EMB + bcol;

  short8 ab[2];
  f32x4  af[4];
  short8 wb[4];
  if constexpr (ABF) {
    ab[0] = *(const short8*)((const ushort*)Ap + aoff);
    ab[1] = *(const short8*)((const ushort*)Ap + aoff + 8);
  } else {
#pragma unroll
    for (int i = 0; i < 4; ++i) af[i] = *(const f32x4*)((const float*)Ap + aoff + 4 * i);
  }
#pragma unroll
  for (int i = 0; i < 4; ++i) wb[i] = *(const short8*)(Wp + boff + 8 * i);

  for (int k0 = 0; k0 < EMB; k0 += 64) {
    __syncthreads();
    if constexpr (ABF) {
      *(short8*)&As[arow * LDP + acol]     = ab[0];
      *(short8*)&As[arow * LDP + acol + 8] = ab[1];
    } else {
      *(short8*)&As[arow * LDP + acol]     = pack8(af[0], af[1]);
      *(short8*)&As[arow * LDP + acol + 8] = pack8(af[2], af[3]);
    }
#pragma unroll
    for (int i = 0; i < 4; ++i) *(short8*)&Ws[brow * LDP + bcol + 8 * i] = wb[i];
    if (k0 + 64 < EMB) {
      if constexpr (ABF) {
        ab[0] = *(const short8*)((const ushort*)Ap + aoff + k0 + 64);
        ab[1] = *(const short8*)((const ushort*)Ap + aoff + k0 + 64 + 8);
      } else {
#pragma unroll
        for (int i = 0; i < 4; ++i)
          af[i] = *(const f32x4*)((const float*)Ap + aoff + k0 + 64 + 4 * i);
      }
#pragma unroll
      for (int i = 0; i < 4; ++i) wb[i] = *(const short8*)(Wp + boff + k0 + 64 + 8 * i);
    }
    __syncthreads();

#pragma unroll
    for (int ks = 0; ks < 2; ++ks) {
      short8 a_[4], b_[2];
#pragma unroll
      for (int i = 0; i < 4; ++i)
        a_[i] = *(const short8*)&As[(i * 16 + l16) * LDP + ks * 32 + quad * 8];
#pragma unroll
      for (int i = 0; i < 2; ++i)
        b_[i] = *(const short8*)&Ws[(w * 32 + i * 16 + l16) * LDP + ks * 32 + quad * 8];
#pragma unroll
      for (int mi = 0; mi < 4; ++mi)
#pragma unroll
        for (int ni = 0; ni < 2; ++ni)
          acc[mi][ni] = __builtin_amdgcn_mfma_f32_16x16x32_bf16(a_[mi], b_[ni], acc[mi][ni], 0, 0, 0);
    }
  }
}

// QKV epilogue (64-row tile): Q (pre-scaled) / K head-major; V^T [B][H][HD][T]
__device__ __forceinline__ void qkv_epi64(f32x4 acc[4][2], int mt, int n0, int mat,
                                          const void* bias, int isbf,
                                          ushort* qo, ushort* ko, ushort* vo) {
  const int tid  = threadIdx.x;
  const int w    = tid >> 6;
  const int lane = tid & 63;
  const int quad = lane >> 4;
  const int l16  = lane & 15;
  ushort* dst = (mat == 0) ? qo : ko;
  const float sc = (mat == 0) ? CSCALE : 1.0f;

#pragma unroll
  for (int ni = 0; ni < 2; ++ni) {
    const int n = n0 + w * 32 + ni * 16 + l16;
    const float bv_ = isbf ? bf2f(((const ushort*)bias)[n]) : ((const float*)bias)[n];
    const int hh = n >> 6, d = n & 63;
#pragma unroll
    for (int mi = 0; mi < 4; ++mi) {
      const int mbase = mt * 64 + mi * 16 + quad * 4;
      const int b = mbase >> 11, t = mbase & (TT - 1);
      if (mat == 2) {
        us4 pk;
#pragma unroll
        for (int r = 0; r < 4; ++r) pk[r] = f2bf(acc[mi][ni][r] + bv_);
        *(us4*)&vo[((size_t)((b * HEADS + hh) * HD + d)) * TT + t] = pk;
      } else {
#pragma unroll
        for (int r = 0; r < 4; ++r)
          dst[((size_t)((b * HEADS + hh) * TT + t + r)) * HD + d] = f2bf((acc[mi][ni][r] + bv_) * sc);
      }
    }
  }
}

__global__ __launch_bounds__(256) void qkv_pipe(const void* __restrict__ x,
                                                const ushort* __restrict__ w3,
                                                const void* __restrict__ bq,
                                                const void* __restrict__ bk,
                                                const void* __restrict__ bv,
                                                ushort* __restrict__ qo,
                                                ushort* __restrict__ ko,
                                                ushort* __restrict__ vo,
                                                const int* __restrict__ flag) {
  __shared__ __align__(16) ushort As[64 * LDP];
  __shared__ __align__(16) ushort Ws[128 * LDP];
  // XCD swizzle: each XCD covers 3 n-tiles -> its 0.75 MB W-slice is L2-resident
  const int xcd = blockIdx.x & 7;
  const int i   = blockIdx.x >> 3;       // 0..191
  const int nt  = xcd * 3 + (i % 3);     // 0..23
  const int mt  = i / 3;                 // 0..63
  const int mat = nt >> 3;
  const int n0  = (nt & 7) * 128;
  const ushort* W  = w3 + (size_t)mat * ELW;
  const void* bias = (mat == 0) ? bq : (mat == 1) ? bk : bv;

  f32x4 acc[4][2];
#pragma unroll
  for (int a = 0; a < 4; ++a)
#pragma unroll
    for (int b = 0; b < 2; ++b) acc[a][b] = (f32x4){0.f, 0.f, 0.f, 0.f};

  const int isbf = *flag;
  if (isbf) gemm_qkv64<true >(x, W, mt * 64, n0, As, Ws, acc);
  else      gemm_qkv64<false>(x, W, mt * 64, n0, As, Ws, acc);
  qkv_epi64(acc, mt, n0, mat, bias, isbf, qo, ko, vo);
}

// ---------------------------------------------------------------------------
// Causal flash attention with register-prefetched K/V staging.
// Fixed-max softmax. Balanced qt swizzle.
// ---------------------------------------------------------------------------
__global__ __launch_bounds__(256) void attn3(const ushort* __restrict__ qw,
                                             const ushort* __restrict__ kw,
                                             const ushort* __restrict__ vtw,
                                             ushort* __restrict__ out) {
  __shared__ __align__(16) ushort Ks[64 * LDA];
  __shared__ __align__(16) ushort Vts[64 * LDA];
  __shared__ __align__(16) ushort Ps[4][16 * LDA];

  const int bid = blockIdx.x;
  const int j  = bid >> 8;
  const int r8 = bid & 255;
  const int qh = r8 & 31;
  const int bh = j * 8 + (r8 >> 5);
  int qt;
  if      (j == 0) qt = qh;
  else if (j == 1) qt = 31 - qh;
  else if (j == 2) qt = (qh + 16) & 31;
  else             qt = 31 - ((qh + 16) & 31);
  const int h = bh & (HEADS - 1);
  const int b = bh >> 4;

  const int tid  = threadIdx.x;
  const int w    = tid >> 6;
  const int lane = tid & 63;
  const int quad = lane >> 4;
  const int l16  = lane & 15;

  const size_t hoff = ((size_t)(b * HEADS + h)) * TT * HD;
  const ushort* Qg = qw + hoff;
  const ushort* Kg = kw + hoff;
  const ushort* Vg = vtw + hoff;     // [d][T]
  const int q0 = qt * 64;

  short8 qf[2];
  {
    const ushort* qrow = Qg + (size_t)(q0 + w * 16 + l16) * HD;
    qf[0] = *(const short8*)(qrow + quad * 8);
    qf[1] = *(const short8*)(qrow + 32 + quad * 8);
  }

  const int row = tid >> 2;
  const int c0  = (tid & 3) * 16;
  const ushort* Kbase = Kg + (size_t)row * HD + c0;
  const ushort* Vbase = Vg + (size_t)row * TT + c0;

  short8 pk0 = *(const short8*)(Kbase);
  short8 pk1 = *(const short8*)(Kbase + 8);
  short8 pv0 = *(const short8*)(Vbase);
  short8 pv1 = *(const short8*)(Vbase + 8);

  float ls[4] = {0.f, 0.f, 0.f, 0.f};
  f32x4 O[4];
#pragma unroll
  for (int ni = 0; ni < 4; ++ni) O[ni] = (f32x4){0.f, 0.f, 0.f, 0.f};

  for (int kt = 0; kt <= qt; ++kt) {
    const int k0 = kt * 64;
    __syncthreads();
    *(short8*)&Ks[row * LDA + c0]      = pk0;
    *(short8*)&Ks[row * LDA + c0 + 8]  = pk1;
    *(short8*)&Vts[row * LDA + c0]     = pv0;
    *(short8*)&Vts[row * LDA + c0 + 8] = pv1;
    if (kt < qt) {
      const size_t ko_ = (size_t)(k0 + 64) * HD;
      pk0 = *(const short8*)(Kbase + ko_);
      pk1 = *(const short8*)(Kbase + ko_ + 8);
      pv0 = *(const short8*)(Vbase + k0 + 64);
      pv1 = *(const short8*)(Vbase + k0 + 64 + 8);
    }
    __syncthreads();

    f32x4 s[4];
#pragma unroll
    for (int ni = 0; ni < 4; ++ni) s[ni] = (f32x4){0.f, 0.f, 0.f, 0.f};
#pragma unroll
    for (int ks = 0; ks < 2; ++ks) {
#pragma unroll
      for (int ni = 0; ni < 4; ++ni) {
        short8 kb = *(const short8*)&Ks[(ni * 16 + l16) * LDA + ks * 32 + quad * 8];
        s[ni] = __builtin_amdgcn_mfma_f32_16x16x32_bf16(qf[ks], kb, s[ni], 0, 0, 0);
      }
    }

    if (kt == qt) {
#pragma unroll
      for (int ni = 0; ni < 4; ++ni) {
        const int kk = k0 + ni * 16 + l16;
#pragma unroll
        for (int r = 0; r < 4; ++r) {
          const int qq = q0 + w * 16 + quad * 4 + r;
          if (kk > qq) s[ni][r] = -__builtin_inff();
        }
      }
    }

#pragma unroll
    for (int ni = 0; ni < 4; ++ni)
#pragma unroll
      for (int r = 0; r < 4; ++r) {
        const float p = exp2f(s[ni][r]);
        s[ni][r] = p;
        ls[r] += p;
      }

#pragma unroll
    for (int ni = 0; ni < 4; ++ni)
#pragma unroll
      for (int r = 0; r < 4; ++r)
        Ps[w][(quad * 4 + r) * LDA + ni * 16 + l16] = f2bf_trunc(s[ni][r]);

#pragma unroll
    for (int ks = 0; ks < 2; ++ks) {
      short8 a = *(const short8*)&Ps[w][l16 * LDA + ks * 32 + quad * 8];
#pragma unroll
      for (int ni = 0; ni < 4; ++ni) {
        short8 vb = *(const short8*)&Vts[(ni * 16 + l16) * LDA + ks * 32 + quad * 8];
        O[ni] = __builtin_amdgcn_mfma_f32_16x16x32_bf16(a, vb, O[ni], 0, 0, 0);
      }
    }
  }

#pragma unroll
  for (int r = 0; r < 4; ++r) {
#pragma unroll
    for (int off = 1; off < 16; off <<= 1) ls[r] += __shfl_xor(ls[r], off);
    const float inv = 1.0f / ls[r];
    const int t = q0 + w * 16 + quad * 4 + r;
#pragma unroll
    for (int ni = 0; ni < 4; ++ni) {
      out[((size_t)(b * TT + t)) * EMB + h * HD + ni * 16 + l16] = f2bf(O[ni][r] * inv);
    }
  }
}

// ---------------------------------------------------------------------------
// Output projection: 64x128 tiles, BK=32, register prefetch, 512 blocks.
// ---------------------------------------------------------------------------
template<bool BF> struct PF {
  short8 b0, b1;
  f32x4 f0, f1, f2, f3;
  __device__ __forceinline__ void load(const void* base, size_t i0, size_t i1) {
    if constexpr (BF) {
      b0 = *(const short8*)((const ushort*)base + i0);
      b1 = *(const short8*)((const ushort*)base + i1);
    } else {
      const float* p0 = (const float*)base + i0;
      const float* p1 = (const float*)base + i1;
      f0 = *(const f32x4*)p0; f1 = *(const f32x4*)(p0 + 4);
      f2 = *(const f32x4*)p1; f3 = *(const f32x4*)(p1 + 4);
    }
  }
  __device__ __forceinline__ void store(ushort* l0, ushort* l1) {
    if constexpr (BF) { *(short8*)l0 = b0; *(short8*)l1 = b1; }
    else { *(short8*)l0 = pack8(f0, f1); *(short8*)l1 = pack8(f2, f3); }
  }
};

template<bool WBF>
__device__ __forceinline__ void proj_core(const ushort* __restrict__ A,
                                          const void* __restrict__ Wo,
                                          int m0, int n0,
                                          ushort* As, ushort* Ws,
                                          f32x4 acc[4][2]) {
  const int tid  = threadIdx.x;
  const int w    = tid >> 6;
  const int lane = tid & 63;
  const int quad = lane >> 4;
  const int l16  = lane & 15;
  const int srow = tid >> 2;
  const int scol = (tid & 3) * 8;

  const size_t ai = (size_t)(m0 + srow) * EMB + scol;
  const size_t b0 = (size_t)(n0 + srow) * EMB + scol;
  const size_t b1 = (size_t)(n0 + srow + 64) * EMB + scol;

  short8 pa;
  PF<WBF> pb;
  pa = *(const short8*)(A + ai);
  pb.load(Wo, b0, b1);

  for (int k0 = 0; k0 < EMB; k0 += 32) {
    __syncthreads();
    *(short8*)&As[srow * 32 + scol] = pa;
    pb.store(&Ws[srow * 32 + scol], &Ws[(srow + 64) * 32 + scol]);
    if (k0 + 32 < EMB) {
      pa = *(const short8*)(A + ai + k0 + 32);
      pb.load(Wo, b0 + k0 + 32, b1 + k0 + 32);
    }
    __syncthreads();

    short8 af[4], bfr[2];
#pragma unroll
    for (int i = 0; i < 4; ++i)
      af[i]  = *(const short8*)&As[(i * 16 + l16) * 32 + quad * 8];
#pragma unroll
    for (int i = 0; i < 2; ++i)
      bfr[i] = *(const short8*)&Ws[(w * 32 + i * 16 + l16) * 32 + quad * 8];
#pragma unroll
    for (int mi = 0; mi < 4; ++mi)
#pragma unroll
      for (int ni = 0; ni < 2; ++ni)
        acc[mi][ni] = __builtin_amdgcn_mfma_f32_16x16x32_bf16(af[mi], bfr[ni], acc[mi][ni], 0, 0, 0);
  }
}

__global__ __launch_bounds__(256) void proj_pipe(const ushort* __restrict__ A,
                                                 const void* __restrict__ Wo,
                                                 const void* __restrict__ bo,
                                                 void* __restrict__ out,
                                                 const int* __restrict__ flag) {
  __shared__ __align__(16) ushort As[64 * 32];
  __shared__ __align__(16) ushort Ws[128 * 32];
  const int nt = blockIdx.x & 7;
  const int mt = blockIdx.x >> 3;
  const int n0 = nt * 128;
  const int m0 = mt * 64;

  f32x4 acc[4][2];
#pragma unroll
  for (int i = 0; i < 4; ++i)
#pragma unroll
    for (int jj = 0; jj < 2; ++jj) acc[i][jj] = (f32x4){0.f, 0.f, 0.f, 0.f};

  const int isbf = *flag;
  if (isbf) proj_core<true >(A, Wo, m0, n0, As, Ws, acc);
  else      proj_core<false>(A, Wo, m0, n0, As, Ws, acc);

  const int tid  = threadIdx.x;
  const int w    = tid >> 6;
  const int lane = tid & 63;
  const int quad = lane >> 4;
  const int l16  = lane & 15;

#pragma unroll
  for (int ni = 0; ni < 2; ++ni) {
    const int n = n0 + w * 32 + ni * 16 + l16;
    const float bv_ = isbf ? bf2f(((const ushort*)bo)[n]) : ((const float*)bo)[n];
#pragma unroll
    for (int mi = 0; mi < 4; ++mi) {
#pragma unroll
      for (int r = 0; r < 4; ++r) {
        const int m = m0 + mi * 16 + quad * 4 + r;
        const float v = acc[mi][ni][r] + bv_;
        if (isbf) ((ushort*)out)[(size_t)m * EMB + n] = f2bf(v);
        else      ((float*) out)[(size_t)m * EMB + n] = v;
      }
    }
  }
}

// ---------------------------------------------------------------------------
extern "C" void kernel_launch(void* const* d_in, const int* in_sizes, int n_in,
                              void* d_out, int out_size, void* d_ws, size_t ws_size,
                              hipStream_t stream) {
  const void* x  = d_in[0];
  const void* Wq = d_in[1];
  const void* bq = d_in[2];
  const void* Wk = d_in[3];
  const void* bk = d_in[4];
  const void* Wv = d_in[5];
  const void* bv = d_in[6];
  const void* Wo = d_in[7];
  const void* bo = d_in[8];

  int* flag = (int*)d_ws;
  ushort* base = (ushort*)((char*)d_ws + 256);

  // ws layout (33.56 MB budget):
  //   q:[0,ELX) k:[ELX,2ELX) vt:[2ELX,3ELX)
  //   w3 (3*ELW, dead after qkv) and o (ELX) share [3ELX,4ELX)
  ushort* q_ws  = base;
  ushort* k_ws  = q_ws + ELX;
  ushort* vt_ws = k_ws + ELX;
  ushort* w3    = vt_ws + ELX;
  ushort* o_ws  = vt_ws + ELX;

  detect_dtype<<<dim3(1), dim3(64), 0, stream>>>((const uint32_t*)x, flag);
  convert3<<<dim3(1536), dim3(256), 0, stream>>>(Wq, Wk, Wv, w3, flag);
  qkv_pipe<<<dim3(1536), dim3(256), 0, stream>>>(x, w3, bq, bk, bv,
                                                 q_ws, k_ws, vt_ws, flag);
  attn3<<<dim3(1024), dim3(256), 0, stream>>>(q_ws, k_ws, vt_ws, o_ws);
  proj_pipe<<<dim3(512), dim3(256), 0, stream>>>(o_ws, Wo, bo, d_out, flag);
}